// Round 2
// baseline (788.905 us; speedup 1.0000x reference)
//
#include <hip/hip_runtime.h>
#include <math.h>

#define N_ROWS 262144
#define KCODES 512
#define DIM 64
#define BLOCK 256              // 4 waves x 32 rows = 128 rows/block
#define ROWS_PER_BLOCK 128
// Interleaved B-plane layout: per code, per quad q: 48 ushorts =
// [h(k=q*8..+7), h(k=32+q*8..+7), m(..), m(..), l(..), l(..)] -> 96 B.
// One vaddr per sub-step, 6 x 16B loads at imm offsets 0/16/32/48/64/80.
#define CODE_STRIDE 192        // ushorts per code (64 dims x 3 planes)

typedef __attribute__((ext_vector_type(8))) short short8;   // 8 bf16 = 4 VGPRs
typedef __attribute__((ext_vector_type(4))) float f4;       // MFMA acc / 16B vec

// Output layout (flat fp32, reference return order):
static const size_t OFF_LOSS = 0;
static const size_t OFF_Q    = 1;
static const size_t OFF_PERP = 1 + (size_t)N_ROWS * DIM;
static const size_t OFF_ENC  = OFF_PERP + 1;
static const size_t OFF_IDX  = OFF_ENC + (size_t)N_ROWS * KCODES;

__device__ __forceinline__ unsigned short bf16rne(float f) {
    unsigned int u = __float_as_uint(f);
    u = (u + 0x7fffu + ((u >> 16) & 1u)) >> 16;
    return (unsigned short)u;
}
__device__ __forceinline__ float bf16tof(unsigned short h) {
    return __uint_as_float(((unsigned int)h) << 16);
}

// Kernel 1: L2-normalize embedding rows, 3-way bf16 split, interleaved layout.
__global__ __launch_bounds__(64) void vq_prep(const float* __restrict__ emb,
                                              unsigned short* __restrict__ pe,
                                              float* __restrict__ out_loss,
                                              float* __restrict__ out_perp) {
    int k = blockIdx.x;
    int d = threadIdx.x;
    float v = emb[k * DIM + d];
    float s = v * v;
    #pragma unroll
    for (int off = 32; off > 0; off >>= 1) s += __shfl_xor(s, off, 64);
    float vn = v / fmaxf(sqrtf(s), 1e-12f);
    unsigned short h = bf16rne(vn);
    float r = vn - bf16tof(h);
    unsigned short m = bf16rne(r);
    r = r - bf16tof(m);
    unsigned short l = bf16rne(r);
    // dim d -> k-step s = d>>5, quad qq = (d>>3)&3, elem j = d&7
    int ss = d >> 5, qq = (d >> 3) & 3, j = d & 7;
    unsigned short* base = pe + k * CODE_STRIDE + qq * 48;
    base[ss * 8 + j]      = h;
    base[16 + ss * 8 + j] = m;
    base[32 + ss * 8 + j] = l;
    if (k == 0 && d == 0) { *out_loss = 0.0f; *out_perp = 1.0f; }
}

#define MFMA(A, B, C) C = __builtin_amdgcn_mfma_f32_16x16x32_bf16(A, B, C, 0, 0, 0)

// Kernel 2: no LDS, no barriers. B frags direct from L2-resident planes;
// enc zero-rows streamed inside the MFMA loop; one-hot patched after vmcnt(0).
__global__ __launch_bounds__(BLOCK, 3) void vq_main(const float* __restrict__ x,
                                                    const int* __restrict__ labels,
                                                    const float* __restrict__ emb,
                                                    const unsigned short* __restrict__ pe,
                                                    float* __restrict__ out_loss,
                                                    float* __restrict__ out_q,
                                                    float* __restrict__ out_enc,
                                                    float* __restrict__ out_idx) {
    const int tid   = threadIdx.x;
    const int wv    = tid >> 6;
    const int lane  = tid & 63;
    const int q     = lane >> 4;       // quad 0..3
    const int c     = lane & 15;
    const int wbase = blockIdx.x * ROWS_PER_BLOCK + wv * 32;  // wave owns 32 rows

    // ---- A fragments + per-row inverse norms + 3-way bf16 split.
    float inv_nx[2];
    short8 Ah[2][2], Am[2][2], Al[2][2];
    #pragma unroll
    for (int t = 0; t < 2; ++t) {
        float xv[16];
        const float* xp = x + (size_t)(wbase + t * 16 + c) * DIM + q * 8;
        #pragma unroll
        for (int s = 0; s < 2; ++s) {
            float4 lo = *(const float4*)(xp + s * 32);
            float4 hi = *(const float4*)(xp + s * 32 + 4);
            xv[s * 8 + 0] = lo.x; xv[s * 8 + 1] = lo.y;
            xv[s * 8 + 2] = lo.z; xv[s * 8 + 3] = lo.w;
            xv[s * 8 + 4] = hi.x; xv[s * 8 + 5] = hi.y;
            xv[s * 8 + 6] = hi.z; xv[s * 8 + 7] = hi.w;
        }
        float s2 = 0.f;
        #pragma unroll
        for (int j = 0; j < 16; ++j) s2 = fmaf(xv[j], xv[j], s2);
        s2 += __shfl_xor(s2, 16, 64);
        s2 += __shfl_xor(s2, 32, 64);
        inv_nx[t] = 1.0f / fmaxf(sqrtf(s2), 1e-12f);
        // 3-way bf16 split (no normalization: argmax-invariant).
        #pragma unroll
        for (int s = 0; s < 2; ++s)
            #pragma unroll
            for (int j = 0; j < 8; ++j) {
                float v = xv[s * 8 + j];
                unsigned short h = bf16rne(v);
                float r = v - bf16tof(h);
                unsigned short m = bf16rne(r);
                r = r - bf16tof(m);
                unsigned short l = bf16rne(r);
                Ah[t][s][j] = (short)h;
                Am[t][s][j] = (short)m;
                Al[t][s][j] = (short)l;
            }
    }

    // labels for this lane's 8 C-rows (rows t*16 + q*4 + r)
    int   lbl[2][4];
    float best[2][4], pick[2][4];
    int   bidx[2][4];
    #pragma unroll
    for (int t = 0; t < 2; ++t)
        #pragma unroll
        for (int r = 0; r < 4; ++r) {
            lbl[t][r]  = labels[wbase + t * 16 + q * 4 + r];
            best[t][r] = -3.4e38f;
            bidx[t][r] = 0;
            pick[t][r] = 0.f;
        }

    // ---- main loop: 32 sub-steps of 16 codes, zero LDS, zero barriers.
    #pragma unroll 2
    for (int st = 0; st < KCODES / 16; ++st) {
        const unsigned short* bp = pe + (size_t)(st * 16 + c) * CODE_STRIDE + q * 48;
        short8 Bh0 = *(const short8*)(bp);
        short8 Bh1 = *(const short8*)(bp + 8);
        short8 Bm0 = *(const short8*)(bp + 16);
        short8 Bm1 = *(const short8*)(bp + 24);
        short8 Bl0 = *(const short8*)(bp + 32);
        short8 Bl1 = *(const short8*)(bp + 40);

        // Stream one zero enc row per sub-step while B loads are in flight
        // (32 steps x 1 row = the wave's 32 rows; 2x16B/lane = full 2KB row).
        {
            float* zb = out_enc + (size_t)(wbase + st) * KCODES;
            f4 z = {0.f, 0.f, 0.f, 0.f};
            __builtin_nontemporal_store(z, (f4*)(zb + lane * 4));
            __builtin_nontemporal_store(z, (f4*)(zb + 256 + lane * 4));
        }

        f4 acc0 = {0.f, 0.f, 0.f, 0.f};
        f4 acc1 = {0.f, 0.f, 0.f, 0.f};
        // 6 split-products x 2 K-steps, both M-tiles (B reused 2x).
        MFMA(Ah[0][0], Bh0, acc0);  MFMA(Ah[1][0], Bh0, acc1);
        MFMA(Ah[0][1], Bh1, acc0);  MFMA(Ah[1][1], Bh1, acc1);
        MFMA(Ah[0][0], Bm0, acc0);  MFMA(Ah[1][0], Bm0, acc1);
        MFMA(Ah[0][1], Bm1, acc0);  MFMA(Ah[1][1], Bm1, acc1);
        MFMA(Am[0][0], Bh0, acc0);  MFMA(Am[1][0], Bh0, acc1);
        MFMA(Am[0][1], Bh1, acc0);  MFMA(Am[1][1], Bh1, acc1);
        MFMA(Ah[0][0], Bl0, acc0);  MFMA(Ah[1][0], Bl0, acc1);
        MFMA(Ah[0][1], Bl1, acc0);  MFMA(Ah[1][1], Bl1, acc1);
        MFMA(Al[0][0], Bh0, acc0);  MFMA(Al[1][0], Bh0, acc1);
        MFMA(Al[0][1], Bh1, acc0);  MFMA(Al[1][1], Bh1, acc1);
        MFMA(Am[0][0], Bm0, acc0);  MFMA(Am[1][0], Bm0, acc1);
        MFMA(Am[0][1], Bm1, acc0);  MFMA(Am[1][1], Bm1, acc1);

        const int code = st * 16 + c;  // this lane's column
        #pragma unroll
        for (int r = 0; r < 4; ++r) {
            float d0 = acc0[r];
            if (d0 > best[0][r]) { best[0][r] = d0; bidx[0][r] = code; }
            if (code == lbl[0][r]) pick[0][r] = d0;
            float d1 = acc1[r];
            if (d1 > best[1][r]) { best[1][r] = d1; bidx[1][r] = code; }
            if (code == lbl[1][r]) pick[1][r] = d1;
        }
    }

    // Order the zero-stream before the 1.0 patches (same-address, cross-lane).
    asm volatile("s_waitcnt vmcnt(0)" ::: "memory");

    // Cross-lane argmax reduce within 16-lane col groups (tie -> smaller idx
    // = first max, matching jnp.argmax); pick is one-hot so sum-reduce.
    // Butterfly leaves results on ALL lanes of each group.
    #pragma unroll
    for (int t = 0; t < 2; ++t)
        #pragma unroll
        for (int r = 0; r < 4; ++r) {
            float b = best[t][r]; int i = bidx[t][r]; float p = pick[t][r];
            #pragma unroll
            for (int m = 1; m < 16; m <<= 1) {
                float ob = __shfl_xor(b, m, 64);
                int   oi = __shfl_xor(i, m, 64);
                p += __shfl_xor(p, m, 64);
                if (ob > b || (ob == b && oi < i)) { b = ob; i = oi; }
            }
            bidx[t][r] = i; pick[t][r] = p;
        }

    // One-hot patch + idx: owner lanes (c==0) handle their quad's 8 rows.
    if (c == 0) {
        #pragma unroll
        for (int t = 0; t < 2; ++t)
            #pragma unroll
            for (int r = 0; r < 4; ++r) {
                int row = wbase + t * 16 + q * 4 + r;
                out_enc[(size_t)row * KCODES + bidx[t][r]] = 1.0f;
                out_idx[row] = (float)bidx[t][r];
            }
    }

    // quantized = raw emb row at argmax. Lane's quad owns rows q*4+r; bidx is
    // lane-local after the reduce. 4 rows per pass, element c, coalesced 16B.
    #pragma unroll
    for (int t = 0; t < 2; ++t)
        #pragma unroll
        for (int r = 0; r < 4; ++r) {
            int row = wbase + t * 16 + q * 4 + r;
            f4 v = ((const f4*)(emb + (size_t)bidx[t][r] * DIM))[c];
            __builtin_nontemporal_store(v, ((f4*)(out_q + (size_t)row * DIM)) + c);
        }

    // loss = mean(1 - dist[row, label_row]); dist = split-dot * inv_norm.
    // Each quad's 16 lanes duplicate its 8 rows -> scale by 1/16.
    float lv = 0.f;
    #pragma unroll
    for (int t = 0; t < 2; ++t)
        #pragma unroll
        for (int r = 0; r < 4; ++r) {
            float invv = __shfl(inv_nx[t], q * 4 + r, 64);  // row t*16+q*4+r
            lv += (1.0f - pick[t][r] * invv);
        }
    lv *= 1.0f / ((float)N_ROWS * 16.0f);
    #pragma unroll
    for (int m = 1; m < 64; m <<= 1) lv += __shfl_xor(lv, m, 64);
    if (lane == 0) atomicAdd(out_loss, lv);
}

extern "C" void kernel_launch(void* const* d_in, const int* in_sizes, int n_in,
                              void* d_out, int out_size, void* d_ws, size_t ws_size,
                              hipStream_t stream) {
    const float* x      = (const float*)d_in[0];
    const int*   labels = (const int*)d_in[1];
    const float* emb    = (const float*)d_in[2];
    float* out = (float*)d_out;
    unsigned short* pe = (unsigned short*)d_ws;   // 192 KB interleaved planes

    hipLaunchKernelGGL(vq_prep, dim3(KCODES), dim3(64), 0, stream,
                       emb, pe, out + OFF_LOSS, out + OFF_PERP);
    hipLaunchKernelGGL(vq_main, dim3(N_ROWS / ROWS_PER_BLOCK), dim3(BLOCK), 0, stream,
                       x, labels, emb, pe,
                       out + OFF_LOSS, out + OFF_Q, out + OFF_ENC, out + OFF_IDX);
}

// Round 4
// 737.360 us; speedup vs baseline: 1.0699x; 1.0699x over previous
//
#include <hip/hip_runtime.h>
#include <math.h>

#define N_ROWS 262144
#define KCODES 512
#define DIM 64
#define BLOCK 256              // 4 waves x 32 rows = 128 rows/block
#define ROWS_PER_BLOCK 128
#define KTILE 64               // codes staged per LDS tile
#define NSTAGES (KCODES / KTILE)
#define LDS_ROW 72             // 64 + 8 pad bf16 elems = 144 B stride (bank-balanced)
#define PLANE_STRIDE (KTILE * LDS_ROW)   // ushorts

typedef __attribute__((ext_vector_type(8))) short short8;   // 8 bf16 = 4 VGPRs
typedef __attribute__((ext_vector_type(4))) float f4;       // MFMA acc / 16B vec

// Output layout (flat fp32, reference return order):
static const size_t OFF_LOSS = 0;
static const size_t OFF_Q    = 1;
static const size_t OFF_PERP = 1 + (size_t)N_ROWS * DIM;
static const size_t OFF_ENC  = OFF_PERP + 1;
static const size_t OFF_IDX  = OFF_ENC + (size_t)N_ROWS * KCODES;

__device__ __forceinline__ unsigned short bf16rne(float f) {
    unsigned int u = __float_as_uint(f);
    u = (u + 0x7fffu + ((u >> 16) & 1u)) >> 16;
    return (unsigned short)u;
}
__device__ __forceinline__ float bf16tof(unsigned short h) {
    return __uint_as_float(((unsigned int)h) << 16);
}

// Kernel 1: L2-normalize embedding rows, 3-way bf16 split into ws planes.
// x ~= h + m + l with 8 mantissa bits each => (h+m+l) matches fp32 to ~2^-26.
__global__ __launch_bounds__(64) void vq_prep(const float* __restrict__ emb,
                                              unsigned short* __restrict__ ph,
                                              unsigned short* __restrict__ pm,
                                              unsigned short* __restrict__ pl,
                                              float* __restrict__ out_loss,
                                              float* __restrict__ out_perp) {
    int k = blockIdx.x;
    int d = threadIdx.x;
    float v = emb[k * DIM + d];
    float s = v * v;
    #pragma unroll
    for (int off = 32; off > 0; off >>= 1) s += __shfl_xor(s, off, 64);
    float vn = v / fmaxf(sqrtf(s), 1e-12f);
    unsigned short h = bf16rne(vn);
    float r = vn - bf16tof(h);
    unsigned short m = bf16rne(r);
    r = r - bf16tof(m);
    unsigned short l = bf16rne(r);
    ph[k * DIM + d] = h;
    pm[k * DIM + d] = m;
    pl[k * DIM + d] = l;
    if (k == 0 && d == 0) { *out_loss = 0.0f; *out_perp = 1.0f; }
}

#define MFMA(A, B, C) C = __builtin_amdgcn_mfma_f32_16x16x32_bf16(A, B, C, 0, 0, 0)

// Kernel 2: LDS-staged B (coalesced, shared by 4 waves); enc zero-rows
// streamed INSIDE the MFMA loop so the 537 MB write drains under compute;
// one-hot 1.0 patched after vmcnt(0). Shuffle-only epilogue (no LDS arrays).
__global__ __launch_bounds__(BLOCK, 3) void vq_main(const float* __restrict__ x,
                                                    const int* __restrict__ labels,
                                                    const float* __restrict__ emb,
                                                    const unsigned short* __restrict__ ph,
                                                    const unsigned short* __restrict__ pm,
                                                    const unsigned short* __restrict__ pl,
                                                    float* __restrict__ out_loss,
                                                    float* __restrict__ out_q,
                                                    float* __restrict__ out_enc,
                                                    float* __restrict__ out_idx) {
    const int tid   = threadIdx.x;
    const int wv    = tid >> 6;
    const int lane  = tid & 63;
    const int q     = lane >> 4;       // quad 0..3
    const int c     = lane & 15;
    const int wbase = blockIdx.x * ROWS_PER_BLOCK + wv * 32;  // wave owns 32 rows

    __shared__ __align__(16) unsigned short sE[3 * PLANE_STRIDE];  // ~27.6 KB

    // ---- A fragments + per-row inverse norms + 3-way bf16 split.
    float inv_nx[2];
    short8 Ah[2][2], Am[2][2], Al[2][2];
    #pragma unroll
    for (int t = 0; t < 2; ++t) {
        float xv[16];
        const float* xp = x + (size_t)(wbase + t * 16 + c) * DIM + q * 8;
        #pragma unroll
        for (int s = 0; s < 2; ++s) {
            float4 lo = *(const float4*)(xp + s * 32);
            float4 hi = *(const float4*)(xp + s * 32 + 4);
            xv[s * 8 + 0] = lo.x; xv[s * 8 + 1] = lo.y;
            xv[s * 8 + 2] = lo.z; xv[s * 8 + 3] = lo.w;
            xv[s * 8 + 4] = hi.x; xv[s * 8 + 5] = hi.y;
            xv[s * 8 + 6] = hi.z; xv[s * 8 + 7] = hi.w;
        }
        float s2 = 0.f;
        #pragma unroll
        for (int j = 0; j < 16; ++j) s2 = fmaf(xv[j], xv[j], s2);
        s2 += __shfl_xor(s2, 16, 64);
        s2 += __shfl_xor(s2, 32, 64);
        inv_nx[t] = 1.0f / fmaxf(sqrtf(s2), 1e-12f);
        // 3-way bf16 split (no normalization: argmax-invariant).
        #pragma unroll
        for (int s = 0; s < 2; ++s)
            #pragma unroll
            for (int j = 0; j < 8; ++j) {
                float v = xv[s * 8 + j];
                unsigned short h = bf16rne(v);
                float r = v - bf16tof(h);
                unsigned short m = bf16rne(r);
                r = r - bf16tof(m);
                unsigned short l = bf16rne(r);
                Ah[t][s][j] = (short)h;
                Am[t][s][j] = (short)m;
                Al[t][s][j] = (short)l;
            }
    }

    // labels for this lane's 8 C-rows (rows t*16 + q*4 + r)
    int   lbl[2][4];
    float best[2][4], pick[2][4];
    int   bidx[2][4];
    #pragma unroll
    for (int t = 0; t < 2; ++t)
        #pragma unroll
        for (int r = 0; r < 4; ++r) {
            lbl[t][r]  = labels[wbase + t * 16 + q * 4 + r];
            best[t][r] = -3.4e38f;
            bidx[t][r] = 0;
            pick[t][r] = 0.f;
        }

    for (int st = 0; st < NSTAGES; ++st) {
        __syncthreads();
        // Stage 3 planes of 64 codes: 512 16B-chunks/plane, 2 per thread.
        #pragma unroll
        for (int i = 0; i < 2; ++i) {
            int ch = tid + i * BLOCK;
            int code = ch >> 3, part = ch & 7;
            int dst = code * LDS_ROW + part * 8;
            int src = st * (KTILE * DIM) + ch * 8;
            *(float4*)&sE[dst]                    = *(const float4*)(ph + src);
            *(float4*)&sE[PLANE_STRIDE + dst]     = *(const float4*)(pm + src);
            *(float4*)&sE[2 * PLANE_STRIDE + dst] = *(const float4*)(pl + src);
        }
        __syncthreads();

        #pragma unroll 2
        for (int sub = 0; sub < KTILE / 16; ++sub) {
            // B frags: lane holds code (sub*16+c), k = s*32 + q*8 + j — contiguous 16B.
            const unsigned short* bp = &sE[(sub * 16 + c) * LDS_ROW + q * 8];
            short8 Bh0 = *(const short8*)(bp);
            short8 Bh1 = *(const short8*)(bp + 32);
            short8 Bm0 = *(const short8*)(bp + PLANE_STRIDE);
            short8 Bm1 = *(const short8*)(bp + PLANE_STRIDE + 32);
            short8 Bl0 = *(const short8*)(bp + 2 * PLANE_STRIDE);
            short8 Bl1 = *(const short8*)(bp + 2 * PLANE_STRIDE + 32);

            // Stream one zero enc row per substep while LDS reads / MFMA run:
            // 32 substeps x 1 row = the wave's 32 rows; 2x16B/lane = full 2KB row.
            {
                int g = st * (KTILE / 16) + sub;
                float* zb = out_enc + (size_t)(wbase + g) * KCODES;
                f4 z = {0.f, 0.f, 0.f, 0.f};
                __builtin_nontemporal_store(z, (f4*)(zb + lane * 4));
                __builtin_nontemporal_store(z, (f4*)(zb + 256 + lane * 4));
            }

            f4 acc0 = {0.f, 0.f, 0.f, 0.f};
            f4 acc1 = {0.f, 0.f, 0.f, 0.f};
            // 6 split-products x 2 K-steps, both M-tiles (B reused 2x).
            MFMA(Ah[0][0], Bh0, acc0);  MFMA(Ah[1][0], Bh0, acc1);
            MFMA(Ah[0][1], Bh1, acc0);  MFMA(Ah[1][1], Bh1, acc1);
            MFMA(Ah[0][0], Bm0, acc0);  MFMA(Ah[1][0], Bm0, acc1);
            MFMA(Ah[0][1], Bm1, acc0);  MFMA(Ah[1][1], Bm1, acc1);
            MFMA(Am[0][0], Bh0, acc0);  MFMA(Am[1][0], Bh0, acc1);
            MFMA(Am[0][1], Bh1, acc0);  MFMA(Am[1][1], Bh1, acc1);
            MFMA(Ah[0][0], Bl0, acc0);  MFMA(Ah[1][0], Bl0, acc1);
            MFMA(Ah[0][1], Bl1, acc0);  MFMA(Ah[1][1], Bl1, acc1);
            MFMA(Al[0][0], Bh0, acc0);  MFMA(Al[1][0], Bh0, acc1);
            MFMA(Al[0][1], Bh1, acc0);  MFMA(Al[1][1], Bh1, acc1);
            MFMA(Am[0][0], Bm0, acc0);  MFMA(Am[1][0], Bm0, acc1);
            MFMA(Am[0][1], Bm1, acc0);  MFMA(Am[1][1], Bm1, acc1);

            const int code = st * KTILE + sub * 16 + c;  // this lane's column
            #pragma unroll
            for (int r = 0; r < 4; ++r) {
                float d0 = acc0[r];
                if (d0 > best[0][r]) { best[0][r] = d0; bidx[0][r] = code; }
                if (code == lbl[0][r]) pick[0][r] = d0;
                float d1 = acc1[r];
                if (d1 > best[1][r]) { best[1][r] = d1; bidx[1][r] = code; }
                if (code == lbl[1][r]) pick[1][r] = d1;
            }
        }
    }

    // Order the zero-stream before the 1.0 patches (same-address, per-wave).
    asm volatile("s_waitcnt vmcnt(0)" ::: "memory");

    // Cross-lane argmax reduce within 16-lane col groups (tie -> smaller idx
    // = first max, matching jnp.argmax); pick is one-hot so sum-reduce.
    // Butterfly leaves results on ALL lanes of each group.
    #pragma unroll
    for (int t = 0; t < 2; ++t)
        #pragma unroll
        for (int r = 0; r < 4; ++r) {
            float b = best[t][r]; int i = bidx[t][r]; float p = pick[t][r];
            #pragma unroll
            for (int m = 1; m < 16; m <<= 1) {
                float ob = __shfl_xor(b, m, 64);
                int   oi = __shfl_xor(i, m, 64);
                p += __shfl_xor(p, m, 64);
                if (ob > b || (ob == b && oi < i)) { b = ob; i = oi; }
            }
            bidx[t][r] = i; pick[t][r] = p;
        }

    // One-hot patch + idx: owner lanes (c==0) handle their quad's 8 rows.
    if (c == 0) {
        #pragma unroll
        for (int t = 0; t < 2; ++t)
            #pragma unroll
            for (int r = 0; r < 4; ++r) {
                int row = wbase + t * 16 + q * 4 + r;
                out_enc[(size_t)row * KCODES + bidx[t][r]] = 1.0f;
                out_idx[row] = (float)bidx[t][r];
            }
    }

    // quantized = raw emb row at argmax. Lane's quad owns rows q*4+r; bidx is
    // lane-local after the reduce. Element c -> 16 lanes cover the 64-f row.
    #pragma unroll
    for (int t = 0; t < 2; ++t)
        #pragma unroll
        for (int r = 0; r < 4; ++r) {
            int row = wbase + t * 16 + q * 4 + r;
            f4 v = ((const f4*)(emb + (size_t)bidx[t][r] * DIM))[c];
            __builtin_nontemporal_store(v, ((f4*)(out_q + (size_t)row * DIM)) + c);
        }

    // loss = mean(1 - dist[row, label_row]); dist = split-dot * inv_norm.
    // Each quad's 16 lanes duplicate its 8 rows -> scale by 1/16.
    float lv = 0.f;
    #pragma unroll
    for (int t = 0; t < 2; ++t)
        #pragma unroll
        for (int r = 0; r < 4; ++r) {
            float invv = __shfl(inv_nx[t], q * 4 + r, 64);  // row t*16+q*4+r
            lv += (1.0f - pick[t][r] * invv);
        }
    lv *= 1.0f / ((float)N_ROWS * 16.0f);
    #pragma unroll
    for (int m = 1; m < 64; m <<= 1) lv += __shfl_xor(lv, m, 64);
    if (lane == 0) atomicAdd(out_loss, lv);
}

extern "C" void kernel_launch(void* const* d_in, const int* in_sizes, int n_in,
                              void* d_out, int out_size, void* d_ws, size_t ws_size,
                              hipStream_t stream) {
    const float* x      = (const float*)d_in[0];
    const int*   labels = (const int*)d_in[1];
    const float* emb    = (const float*)d_in[2];
    float* out = (float*)d_out;
    unsigned short* ph = (unsigned short*)d_ws;              // 64 KB
    unsigned short* pm = ph + (size_t)KCODES * DIM;          // 64 KB
    unsigned short* pl = pm + (size_t)KCODES * DIM;          // 64 KB (192 KB total)

    hipLaunchKernelGGL(vq_prep, dim3(KCODES), dim3(64), 0, stream,
                       emb, ph, pm, pl, out + OFF_LOSS, out + OFF_PERP);
    hipLaunchKernelGGL(vq_main, dim3(N_ROWS / ROWS_PER_BLOCK), dim3(BLOCK), 0, stream,
                       x, labels, emb, ph, pm, pl,
                       out + OFF_LOSS, out + OFF_Q, out + OFF_ENC, out + OFF_IDX);
}

// Round 5
// 718.247 us; speedup vs baseline: 1.0984x; 1.0266x over previous
//
#include <hip/hip_runtime.h>
#include <math.h>

#define N_ROWS 262144
#define KCODES 512
#define DIM 64
#define BLOCK 256              // 4 waves x 32 rows = 128 rows/block
#define ROWS_PER_BLOCK 128
#define NSUB (KCODES / 16)     // 32 substeps of 16 codes

// Fragment-major B layout (built by vq_prep):
//   pe[((st*6 + f)*64 + lane) * 8 + j]
// st = substep (16 codes), f = plane*2 + khalf (h0,h1,m0,m1,l0,l1),
// lane = q*16 + c holds code st*16+c, k = khalf*32 + q*8 + j.
// => each B-fragment load is 64 lanes x contiguous 16B = 1KB coalesced.

typedef __attribute__((ext_vector_type(8))) short short8;   // 8 bf16 = 4 VGPRs
typedef __attribute__((ext_vector_type(4))) float f4;       // MFMA acc / 16B vec

// Output layout (flat fp32, reference return order):
static const size_t OFF_LOSS = 0;
static const size_t OFF_Q    = 1;
static const size_t OFF_PERP = 1 + (size_t)N_ROWS * DIM;
static const size_t OFF_ENC  = OFF_PERP + 1;
static const size_t OFF_IDX  = OFF_ENC + (size_t)N_ROWS * KCODES;

__device__ __forceinline__ unsigned short bf16rne(float f) {
    unsigned int u = __float_as_uint(f);
    u = (u + 0x7fffu + ((u >> 16) & 1u)) >> 16;
    return (unsigned short)u;
}
__device__ __forceinline__ float bf16tof(unsigned short h) {
    return __uint_as_float(((unsigned int)h) << 16);
}

// Kernel 1: L2-normalize embedding rows, 3-way bf16 split, fragment-major layout.
__global__ __launch_bounds__(64) void vq_prep(const float* __restrict__ emb,
                                              unsigned short* __restrict__ pe,
                                              float* __restrict__ out_loss,
                                              float* __restrict__ out_perp) {
    int k = blockIdx.x;    // code
    int d = threadIdx.x;   // dim
    float v = emb[k * DIM + d];
    float s = v * v;
    #pragma unroll
    for (int off = 32; off > 0; off >>= 1) s += __shfl_xor(s, off, 64);
    float vn = v / fmaxf(sqrtf(s), 1e-12f);
    unsigned short h = bf16rne(vn);
    float r = vn - bf16tof(h);
    unsigned short m = bf16rne(r);
    r = r - bf16tof(m);
    unsigned short l = bf16rne(r);
    // code k -> substep st, col c; dim d -> khalf ss, quad qq, elem j
    int st = k >> 4, cc = k & 15;
    int ss = d >> 5, qq = (d >> 3) & 3, j = d & 7;
    int ln = qq * 16 + cc;
    pe[((size_t)(st * 6 + 0 + ss) * 64 + ln) * 8 + j] = h;   // f = 0,1
    pe[((size_t)(st * 6 + 2 + ss) * 64 + ln) * 8 + j] = m;   // f = 2,3
    pe[((size_t)(st * 6 + 4 + ss) * 64 + ln) * 8 + j] = l;   // f = 4,5
    if (k == 0 && d == 0) { *out_loss = 0.0f; *out_perp = 1.0f; }
}

#define MFMA(A, B, C) C = __builtin_amdgcn_mfma_f32_16x16x32_bf16(A, B, C, 0, 0, 0)

// Kernel 2: ZERO LDS, ZERO BARRIERS. B frags direct from L2 in wave-load
// order (coalesced 1KB per load); enc zero-rows streamed in-loop (no barrier
// ever drains them); one-hot 1.0 patched after vmcnt(0). Shuffle epilogue.
__global__ __launch_bounds__(BLOCK, 3) void vq_main(const float* __restrict__ x,
                                                    const int* __restrict__ labels,
                                                    const float* __restrict__ emb,
                                                    const unsigned short* __restrict__ pe,
                                                    float* __restrict__ out_loss,
                                                    float* __restrict__ out_q,
                                                    float* __restrict__ out_enc,
                                                    float* __restrict__ out_idx) {
    const int tid   = threadIdx.x;
    const int lane  = tid & 63;
    const int q     = lane >> 4;       // quad 0..3
    const int c     = lane & 15;
    const int wbase = blockIdx.x * ROWS_PER_BLOCK + (tid >> 6) * 32;  // wave's 32 rows

    // ---- A fragments + per-row inverse norms + 3-way bf16 split.
    float inv_nx[2];
    short8 Ah[2][2], Am[2][2], Al[2][2];
    #pragma unroll
    for (int t = 0; t < 2; ++t) {
        float xv[16];
        const float* xp = x + (size_t)(wbase + t * 16 + c) * DIM + q * 8;
        #pragma unroll
        for (int s = 0; s < 2; ++s) {
            float4 lo = *(const float4*)(xp + s * 32);
            float4 hi = *(const float4*)(xp + s * 32 + 4);
            xv[s * 8 + 0] = lo.x; xv[s * 8 + 1] = lo.y;
            xv[s * 8 + 2] = lo.z; xv[s * 8 + 3] = lo.w;
            xv[s * 8 + 4] = hi.x; xv[s * 8 + 5] = hi.y;
            xv[s * 8 + 6] = hi.z; xv[s * 8 + 7] = hi.w;
        }
        float s2 = 0.f;
        #pragma unroll
        for (int j = 0; j < 16; ++j) s2 = fmaf(xv[j], xv[j], s2);
        s2 += __shfl_xor(s2, 16, 64);
        s2 += __shfl_xor(s2, 32, 64);
        inv_nx[t] = 1.0f / fmaxf(sqrtf(s2), 1e-12f);
        // 3-way bf16 split (no normalization: argmax-invariant).
        #pragma unroll
        for (int s = 0; s < 2; ++s)
            #pragma unroll
            for (int j = 0; j < 8; ++j) {
                float v = xv[s * 8 + j];
                unsigned short h = bf16rne(v);
                float r = v - bf16tof(h);
                unsigned short m = bf16rne(r);
                r = r - bf16tof(m);
                unsigned short l = bf16rne(r);
                Ah[t][s][j] = (short)h;
                Am[t][s][j] = (short)m;
                Al[t][s][j] = (short)l;
            }
    }

    // labels for this lane's 8 C-rows (rows t*16 + q*4 + r)
    int   lbl[2][4];
    float best[2][4], pick[2][4];
    int   bidx[2][4];
    #pragma unroll
    for (int t = 0; t < 2; ++t)
        #pragma unroll
        for (int r = 0; r < 4; ++r) {
            lbl[t][r]  = labels[wbase + t * 16 + q * 4 + r];
            best[t][r] = -3.4e38f;
            bidx[t][r] = 0;
            pick[t][r] = 0.f;
        }

    // ---- main loop: 32 substeps, no LDS, no barriers.
    #pragma unroll 2
    for (int st = 0; st < NSUB; ++st) {
        const unsigned short* bp = pe + ((size_t)st * 6 * 64 + lane) * 8;
        short8 Bh0 = *(const short8*)(bp);            // f=0: h, k=q*8+j
        short8 Bh1 = *(const short8*)(bp + 512);      // f=1: h, k=32+q*8+j
        short8 Bm0 = *(const short8*)(bp + 1024);
        short8 Bm1 = *(const short8*)(bp + 1536);
        short8 Bl0 = *(const short8*)(bp + 2048);
        short8 Bl1 = *(const short8*)(bp + 2560);

        // Stream one zero enc row per substep (after this substep's loads in
        // program order). No barrier anywhere => drains fully async under
        // compute; vmcnt waits for B loads don't force draining newer stores.
        {
            float* zb = out_enc + (size_t)(wbase + st) * KCODES;
            f4 z = {0.f, 0.f, 0.f, 0.f};
            __builtin_nontemporal_store(z, (f4*)(zb + lane * 4));
            __builtin_nontemporal_store(z, (f4*)(zb + 256 + lane * 4));
        }

        f4 acc0 = {0.f, 0.f, 0.f, 0.f};
        f4 acc1 = {0.f, 0.f, 0.f, 0.f};
        // 6 split-products x 2 K-steps, both M-tiles (B reused 2x).
        MFMA(Ah[0][0], Bh0, acc0);  MFMA(Ah[1][0], Bh0, acc1);
        MFMA(Ah[0][1], Bh1, acc0);  MFMA(Ah[1][1], Bh1, acc1);
        MFMA(Ah[0][0], Bm0, acc0);  MFMA(Ah[1][0], Bm0, acc1);
        MFMA(Ah[0][1], Bm1, acc0);  MFMA(Ah[1][1], Bm1, acc1);
        MFMA(Am[0][0], Bh0, acc0);  MFMA(Am[1][0], Bh0, acc1);
        MFMA(Am[0][1], Bh1, acc0);  MFMA(Am[1][1], Bh1, acc1);
        MFMA(Ah[0][0], Bl0, acc0);  MFMA(Ah[1][0], Bl0, acc1);
        MFMA(Ah[0][1], Bl1, acc0);  MFMA(Ah[1][1], Bl1, acc1);
        MFMA(Al[0][0], Bh0, acc0);  MFMA(Al[1][0], Bh0, acc1);
        MFMA(Al[0][1], Bh1, acc0);  MFMA(Al[1][1], Bh1, acc1);
        MFMA(Am[0][0], Bm0, acc0);  MFMA(Am[1][0], Bm0, acc1);
        MFMA(Am[0][1], Bm1, acc0);  MFMA(Am[1][1], Bm1, acc1);

        const int code = st * 16 + c;  // this lane's column
        #pragma unroll
        for (int r = 0; r < 4; ++r) {
            float d0 = acc0[r];
            if (d0 > best[0][r]) { best[0][r] = d0; bidx[0][r] = code; }
            if (code == lbl[0][r]) pick[0][r] = d0;
            float d1 = acc1[r];
            if (d1 > best[1][r]) { best[1][r] = d1; bidx[1][r] = code; }
            if (code == lbl[1][r]) pick[1][r] = d1;
        }
    }

    // Order this wave's zero-stream before its 1.0 patches (same addresses).
    asm volatile("s_waitcnt vmcnt(0)" ::: "memory");

    // Cross-lane argmax reduce within 16-lane col groups (tie -> smaller idx
    // = first max, matching jnp.argmax); pick is one-hot so sum-reduce.
    // Butterfly leaves results on ALL lanes of each group.
    #pragma unroll
    for (int t = 0; t < 2; ++t)
        #pragma unroll
        for (int r = 0; r < 4; ++r) {
            float b = best[t][r]; int i = bidx[t][r]; float p = pick[t][r];
            #pragma unroll
            for (int m = 1; m < 16; m <<= 1) {
                float ob = __shfl_xor(b, m, 64);
                int   oi = __shfl_xor(i, m, 64);
                p += __shfl_xor(p, m, 64);
                if (ob > b || (ob == b && oi < i)) { b = ob; i = oi; }
            }
            bidx[t][r] = i; pick[t][r] = p;
        }

    // One-hot patch + idx: owner lanes (c==0) handle their quad's 8 rows.
    if (c == 0) {
        #pragma unroll
        for (int t = 0; t < 2; ++t)
            #pragma unroll
            for (int r = 0; r < 4; ++r) {
                int row = wbase + t * 16 + q * 4 + r;
                out_enc[(size_t)row * KCODES + bidx[t][r]] = 1.0f;
                out_idx[row] = (float)bidx[t][r];
            }
    }

    // quantized = raw emb row at argmax. Lane's quad owns rows q*4+r; bidx is
    // lane-local after the reduce. Element c -> 16 lanes cover the 64-f row.
    #pragma unroll
    for (int t = 0; t < 2; ++t)
        #pragma unroll
        for (int r = 0; r < 4; ++r) {
            int row = wbase + t * 16 + q * 4 + r;
            f4 v = ((const f4*)(emb + (size_t)bidx[t][r] * DIM))[c];
            __builtin_nontemporal_store(v, ((f4*)(out_q + (size_t)row * DIM)) + c);
        }

    // loss = mean(1 - dist[row, label_row]); dist = split-dot * inv_norm.
    // Each quad's 16 lanes duplicate its 8 rows -> scale by 1/16.
    float lv = 0.f;
    #pragma unroll
    for (int t = 0; t < 2; ++t)
        #pragma unroll
        for (int r = 0; r < 4; ++r) {
            float invv = __shfl(inv_nx[t], q * 4 + r, 64);  // row t*16+q*4+r
            lv += (1.0f - pick[t][r] * invv);
        }
    lv *= 1.0f / ((float)N_ROWS * 16.0f);
    #pragma unroll
    for (int m = 1; m < 64; m <<= 1) lv += __shfl_xor(lv, m, 64);
    if (lane == 0) atomicAdd(out_loss, lv);
}

extern "C" void kernel_launch(void* const* d_in, const int* in_sizes, int n_in,
                              void* d_out, int out_size, void* d_ws, size_t ws_size,
                              hipStream_t stream) {
    const float* x      = (const float*)d_in[0];
    const int*   labels = (const int*)d_in[1];
    const float* emb    = (const float*)d_in[2];
    float* out = (float*)d_out;
    unsigned short* pe = (unsigned short*)d_ws;   // 192 KB fragment-major planes

    hipLaunchKernelGGL(vq_prep, dim3(KCODES), dim3(64), 0, stream,
                       emb, pe, out + OFF_LOSS, out + OFF_PERP);
    hipLaunchKernelGGL(vq_main, dim3(N_ROWS / ROWS_PER_BLOCK), dim3(BLOCK), 0, stream,
                       x, labels, emb, pe,
                       out + OFF_LOSS, out + OFF_Q, out + OFF_ENC, out + OFF_IDX);
}